// Round 18
// baseline (191.792 us; speedup 1.0000x reference)
//
#include <hip/hip_runtime.h>
#include <math.h>

typedef unsigned short ushort_t;
typedef unsigned int uint_t;
typedef _Float16 half_t;

#define DIMC 128
#define NB 16
#define NL 4096

using f32x4 = __attribute__((ext_vector_type(4))) float;
using bf16x8 = __attribute__((ext_vector_type(8))) short;
using half4 = __attribute__((ext_vector_type(4))) half_t;

__device__ __forceinline__ ushort_t bf16rne(float f) {
  uint_t b = __float_as_uint(f);
  b += 0x7fffu + ((b >> 16) & 1u);
  return (ushort_t)(b >> 16);
}

__device__ __forceinline__ uint_t pkbf(float lo, float hi) {
  union { __bf16 h[2]; uint_t u; } u;
  u.h[0] = (__bf16)lo;   // fptrunc = RNE
  u.h[1] = (__bf16)hi;
  return u.u;
}

__device__ __forceinline__ float bf2f(ushort_t u) {
  return __uint_as_float(((uint_t)u) << 16);
}

// ---------------- kernel 0: coeffs -> B-fragment order, bf16 ----------------
// flat 16B-fragment id (per layer): G = ((ci*8 + n)*4 + s)*64 + l
// element j: col o = n*16 + (l&15); k = ci*128 + s*32 + (l>>4)*8 + j
// k -> trig=k&1, g=(k>>1)&7, i=k>>4 ; value = fk[trig][o][i][g]
__global__ __launch_bounds__(256) void prep_coef_k(const float* __restrict__ fk1,
                                                   const float* __restrict__ fk2,
                                                   ushort_t* __restrict__ coefT) {
  int idx = blockIdx.x * 256 + threadIdx.x;  // fragment id, 65536 total
  int layer = idx >> 15;
  int rem = idx & 32767;
  int ci = rem >> 11;
  int n = (rem >> 8) & 7;
  int s = (rem >> 6) & 3;
  int l = rem & 63;
  int o = n * 16 + (l & 15);
  int kbase = ci * 128 + s * 32 + (l >> 4) * 8;
  const float* src = layer ? fk2 : fk1;
  uint_t p[4];
#pragma unroll
  for (int jj = 0; jj < 4; ++jj) {
    int k0 = kbase + jj * 2;
    int t0 = k0 & 1, g0 = (k0 >> 1) & 7, i0 = k0 >> 4;
    int k1 = k0 + 1;
    int t1 = k1 & 1, g1 = (k1 >> 1) & 7, i1 = k1 >> 4;
    ushort_t a = bf16rne(src[((t0 * DIMC + o) * DIMC + i0) * 8 + g0]);
    ushort_t b = bf16rne(src[((t1 * DIMC + o) * DIMC + i1) * 8 + g1]);
    p[jj] = (uint_t)a | ((uint_t)b << 16);
  }
  uint4 w;
  w.x = p[0]; w.y = p[1]; w.z = p[2]; w.w = p[3];
  *(uint4*)&coefT[idx * 8] = w;
}

// ---------------- kernel 1: LN1 -> FKAN1(MFMA) -> ReLU -> LN2 -> FKAN2(MFMA) ----
// r15 shell (proved spill-free at (256,4), Occ 31%) + r17 math (proved
// accurate + ~2x cheaper chains): 1024 blocks x 4 waves = 4 waves/SIMD.
// Wave (tg,nh) owns 32 tokens x 64 outputs, full K, in-register A fragments.
// featfrag: HW trig start pair sincos(r) / sincos(fract(5r)) selected by hb,
// 3 rotation steps, 4 cvt_pk packs. Angle ds_read preloaded one step ahead.
constexpr int SXH = 132;  // xln row stride in halfwords (rows 8B-aligned)

__global__ __launch_bounds__(256, 4) void fkan_main_k(
    const float* __restrict__ x,
    const float* __restrict__ n1g, const float* __restrict__ n1b,
    const float* __restrict__ fk1b,
    const float* __restrict__ n2g, const float* __restrict__ n2b,
    const float* __restrict__ fk2b,
    const ushort_t* __restrict__ coefT,
    ushort_t* __restrict__ out2,
    float* __restrict__ chanSum, float* __restrict__ chanMax) {

  __shared__ half_t xln[64 * SXH];  // 16.9 KB
  __shared__ float sredS[2][2], sredM[2][2];

  const int tid = threadIdx.x;
  const int bid = blockIdx.x;                       // 1024 blocks = 64 tokens
  const int lane = tid & 63;
  const int wid = tid >> 6;
  const int tg = wid >> 1;                          // token group (32 rows)
  const int nh = wid & 1;                           // output half (64 cols)
  const int rowBase = tg * 32;
  const size_t tileBase = (size_t)bid * 64 * DIMC;

  {  // block x-load: 64 rows x 128 f32, coalesced; fp16 to LDS
    const float4* src = (const float4*)(x + tileBase);
#pragma unroll
    for (int j = 0; j < 8; ++j) {
      int idx = j * 256 + tid;  // 0..2047
      float4 v = src[idx];
      half4 h;
      h.x = (half_t)v.x; h.y = (half_t)v.y; h.z = (half_t)v.z; h.w = (half_t)v.w;
      *(half4*)&xln[(idx >> 5) * SXH + (idx & 31) * 4] = h;
    }
  }
  __syncthreads();

  auto layernorm = [&](const float* gg, const float* bb) {  // 16 rows/wave
    float g0 = gg[lane], g1 = gg[lane + 64];
    float be0 = bb[lane], be1 = bb[lane + 64];
#pragma unroll
    for (int j = 0; j < 16; ++j) {
      int t = wid * 16 + j;
      float v0 = (float)xln[t * SXH + lane], v1 = (float)xln[t * SXH + 64 + lane];
      float s = v0 + v1, q = v0 * v0 + v1 * v1;
#pragma unroll
      for (int m = 1; m < 64; m <<= 1) {
        s += __shfl_xor(s, m, 64);
        q += __shfl_xor(q, m, 64);
      }
      float mean = s * (1.0f / DIMC);
      float var = q * (1.0f / DIMC) - mean * mean;
      float rr = rsqrtf(var + 1e-5f);
      xln[t * SXH + lane] = (half_t)((v0 - mean) * rr * g0 + be0);
      xln[t * SXH + 64 + lane] = (half_t)((v1 - mean) * rr * g1 + be1);
    }
  };

  layernorm(n1g, n1b);
  __syncthreads();

  // In-register A fragment (r8/r11/r15 mapping, test-verified): lane holds
  // harmonics hb*4+1..hb*4+4 of channel ci*8+s*2+(hi>>1),
  // token rowBase + mm*16 + (lane&15).
  const int hi = lane >> 4;
  const int hb = hi & 1;
  const half_t* xfr = &xln[(rowBase + (lane & 15)) * SXH + (hi >> 1)];

  auto angAt = [&](int step, int mm) -> float {
    int st = step & 63;  // wrap at layer end: dead value, safe
    return (float)xfr[mm * 16 * SXH + ((st >> 2) & 15) * 8 + (st & 3) * 2];
  };

  // HW-trig fragment from preloaded angle: start at sincos(a) (hb=0) or
  // sincos(5a) (hb=1) via 2pi-scaled v_sin/v_cos; 3 rotation steps; 4 packs.
  auto featfrag = [&](float a) -> bf16x8 {
    float r = a * 0.15915494309189535f;  // a / (2*pi)
    r = r - floorf(r);
    float s1 = __builtin_amdgcn_sinf(r);
    float c1 = __builtin_amdgcn_cosf(r);
    float r5 = r * 5.0f;
    r5 = r5 - floorf(r5);
    float s5 = __builtin_amdgcn_sinf(r5);
    float c5 = __builtin_amdgcn_cosf(r5);
    float cs = hb ? c5 : c1;
    float ss = hb ? s5 : s1;
    uint_t p0 = pkbf(cs, ss);
    float cn, sn;
    cn = cs * c1 - ss * s1; sn = ss * c1 + cs * s1; cs = cn; ss = sn;
    uint_t p1 = pkbf(cs, ss);
    cn = cs * c1 - ss * s1; sn = ss * c1 + cs * s1; cs = cn; ss = sn;
    uint_t p2 = pkbf(cs, ss);
    cn = cs * c1 - ss * s1; sn = ss * c1 + cs * s1; cs = cn; ss = sn;
    uint_t p3 = pkbf(cs, ss);
    union { uint_t u[4]; bf16x8 v; } r2;
    r2.u[0] = p0; r2.u[1] = p1; r2.u[2] = p2; r2.u[3] = p3;
    return r2.v;
  };

  f32x4 acc[4][2];  // [nt][mm]

  auto ldB = [&](const ushort_t* cbase, int st, bf16x8 (&bf)[4]) {
    int ci = st >> 2, s = st & 3;
#pragma unroll
    for (int nt = 0; nt < 4; ++nt)
      bf[nt] = *(const bf16x8*)(cbase +
          (size_t)((((ci * 8 + nh * 4 + nt) * 4 + s) << 6) + lane) * 8);
  };

  auto mfma8 = [&](bf16x8 a0, bf16x8 a1, bf16x8 (&bf)[4]) {
    __builtin_amdgcn_s_setprio(1);
#pragma unroll
    for (int nt = 0; nt < 4; ++nt) {
      acc[nt][0] = __builtin_amdgcn_mfma_f32_16x16x32_bf16(a0, bf[nt],
                                                           acc[nt][0], 0, 0, 0);
      acc[nt][1] = __builtin_amdgcn_mfma_f32_16x16x32_bf16(a1, bf[nt],
                                                           acc[nt][1], 0, 0, 0);
    }
    __builtin_amdgcn_s_setprio(0);
  };

  // barrier-free main loop; B loads issue first, angle preloaded a step
  // ahead, featgen VALU covers both latencies, then the MFMA burst.
  auto run_layer = [&](const ushort_t* cbase) {
#pragma unroll
    for (int nt = 0; nt < 4; ++nt)
#pragma unroll
      for (int mm = 0; mm < 2; ++mm) acc[nt][mm] = (f32x4)(0.f);
    float a0 = angAt(0, 0), a1 = angAt(0, 1);
#pragma unroll 4
    for (int st = 0; st < 64; ++st) {
      bf16x8 bf[4];
      ldB(cbase, st, bf);
      float n0 = angAt(st + 1, 0), n1 = angAt(st + 1, 1);
      bf16x8 f0 = featfrag(a0);
      bf16x8 f1 = featfrag(a1);
      mfma8(f0, f1, bf);
      a0 = n0; a1 = n1;
    }
  };

  run_layer(coefT);
  __syncthreads();  // all waves done reading xln

  // FKAN1 epilogue: bias + ReLU -> xln; nh waves jointly fill full rows
#pragma unroll
  for (int nt = 0; nt < 4; ++nt) {
    int o = (nh * 4 + nt) * 16 + (lane & 15);
    float bia = fk1b[o];
#pragma unroll
    for (int mm = 0; mm < 2; ++mm) {
      int trow = rowBase + mm * 16 + (lane >> 4) * 4;
#pragma unroll
      for (int r = 0; r < 4; ++r)
        xln[(trow + r) * SXH + o] = (half_t)fmaxf(acc[nt][mm][r] + bia, 0.f);
    }
  }
  __syncthreads();

  layernorm(n2g, n2b);
  __syncthreads();

  run_layer(coefT + 262144);

  // FKAN2 epilogue: bias -> out2 (bf16) + partial channel stats (64 cols)
  float ls = 0.f, lm = -INFINITY;
#pragma unroll
  for (int nt = 0; nt < 4; ++nt) {
    int o = (nh * 4 + nt) * 16 + (lane & 15);
    float bia = fk2b[o];
#pragma unroll
    for (int mm = 0; mm < 2; ++mm) {
      int trow = rowBase + mm * 16 + (lane >> 4) * 4;
#pragma unroll
      for (int r = 0; r < 4; ++r) {
        float v = acc[nt][mm][r] + bia;
        out2[tileBase + (size_t)(trow + r) * DIMC + o] = bf16rne(v);
        ls += v;
        lm = fmaxf(lm, v);
      }
    }
  }
#pragma unroll
  for (int m = 1; m < 64; m <<= 1) {
    ls += __shfl_xor(ls, m, 64);
    lm = fmaxf(lm, __shfl_xor(lm, m, 64));
  }
  if (lane == 0) { sredS[tg][nh] = ls; sredM[tg][nh] = lm; }
  __syncthreads();
  if (tid < 2) {  // group id = bid*2 + tg  (tokens [bid*64+tg*32, +32))
    chanSum[bid * 2 + tid] = sredS[tid][0] + sredS[tid][1];
    chanMax[bid * 2 + tid] = fmaxf(sredM[tid][0], sredM[tid][1]);
  }
}

// ---------------- kernel 2: fused tail (VECTORIZED: 2 channels/thread) ----
// Block covers one b and TWO t values; thread (tq = tid>>6, cp = tid&63)
// handles channels {2cp, 2cp+1} of t = t0+tq via ushort2/float2 accesses.
__global__ __launch_bounds__(128) void tail_k(
    const float* __restrict__ x, const ushort_t* __restrict__ out2,
    const float* __restrict__ chanSum, const float* __restrict__ chanMax,
    const float* __restrict__ w1, const float* __restrict__ w2,
    const float* __restrict__ convw, float* __restrict__ dout) {
  int b = blockIdx.x >> 4;
  int t0 = (blockIdx.x & 15) * 2;
  int tid = threadIdx.x;
  int c = tid;           // channel for the MLP phase
  int tq = tid >> 6;
  int cp = tid & 63;
  int t = t0 + tq;
  __shared__ float avs[DIMC], mxs[DIMC], hh[16], cas[DIMC];
  __shared__ float sM[2][134], sX[2][134];

  avs[c] = chanSum[b * DIMC + c] * (1.0f / NL);
  mxs[c] = chanMax[b * DIMC + c];
  __syncthreads();
  if (c < 16) {
    const float* v = (c < 8) ? avs : mxs;
    float a = 0.f;
    for (int i = 0; i < DIMC; ++i) a += v[i] * w1[(c & 7) * DIMC + i];
    hh[c] = fmaxf(a, 0.f);
  }
  __syncthreads();
  {
    float z = 0.f;
#pragma unroll
    for (int r = 0; r < 8; ++r) z += (hh[r] + hh[8 + r]) * w2[c * 8 + r];
    cas[c] = 1.0f / (1.0f + expf(-z));
  }
  __syncthreads();

  const ushort_t* o2b = out2 + (size_t)b * NL * DIMC;
  float s0 = 0.f, s1v = 0.f, m0 = -INFINITY, m1 = -INFINITY;
#pragma unroll 4
  for (int c4 = 0; c4 < 128; ++c4) {
    ushort2 u = *(const ushort2*)&o2b[(size_t)(c4 * 32 + t) * DIMC + 2 * cp];
    float ca = cas[c4];
    float v0 = bf2f(u.x) * ca, v1 = bf2f(u.y) * ca;
    s0 += v0; m0 = fmaxf(m0, v0);
    s1v += v1; m1 = fmaxf(m1, v1);
  }
  sM[tq][2 * cp + 3] = s0 * (1.0f / DIMC); sX[tq][2 * cp + 3] = m0;
  sM[tq][2 * cp + 4] = s1v * (1.0f / DIMC); sX[tq][2 * cp + 4] = m1;
  if (cp < 6) {  // halo positions for this t (zero-padded at sequence edges)
    bool left = cp < 3;
    int tp = left ? t - 1 : t + 1;
    int cc = left ? 125 + cp : cp - 3;
    int di = left ? cp : 131 + (cp - 3);
    float ss = 0.f, mm2 = -INFINITY;
    if (tp >= 0 && tp < 32) {
#pragma unroll 4
      for (int c4 = 0; c4 < 128; ++c4) {
        float v = bf2f(o2b[(size_t)(c4 * 32 + tp) * DIMC + cc]) * cas[c4];
        ss += v;
        mm2 = fmaxf(mm2, v);
      }
      sM[tq][di] = ss * (1.0f / DIMC);
      sX[tq][di] = mm2;
    } else {
      sM[tq][di] = 0.f;
      sX[tq][di] = 0.f;
    }
  }
  __syncthreads();

  float sa0 = 0.f, sa1 = 0.f;
#pragma unroll
  for (int d = 0; d < 7; ++d) {
    float wm = convw[21 + d], wx = convw[70 + d];
    sa0 += wm * sM[tq][2 * cp + d] + wx * sX[tq][2 * cp + d];
    sa1 += wm * sM[tq][2 * cp + 1 + d] + wx * sX[tq][2 * cp + 1 + d];
  }
  float sig0 = 1.0f / (1.0f + expf(-sa0));
  float sig1 = 1.0f / (1.0f + expf(-sa1));

  const float* xb = x + (size_t)b * NL * DIMC;
  float* db = dout + (size_t)b * NL * DIMC;
#pragma unroll 2
  for (int c4 = 0; c4 < 128; ++c4) {
    size_t idx = (size_t)(c4 * 32 + t) * DIMC + 2 * cp;
    float2 xv = *(const float2*)&xb[idx];
    ushort2 u = *(const ushort2*)&o2b[idx];
    float ca = cas[c4];
    float2 dv;
    dv.x = xv.x + bf2f(u.x) * ca * sig0;
    dv.y = xv.y + bf2f(u.y) * ca * sig1;
    *(float2*)&db[idx] = dv;
  }
}

// ---------------- launch ----------------
extern "C" void kernel_launch(void* const* d_in, const int* in_sizes, int n_in,
                              void* d_out, int out_size, void* d_ws, size_t ws_size,
                              hipStream_t stream) {
  const float* x = (const float*)d_in[0];
  const float* n1g = (const float*)d_in[1];
  const float* n1b = (const float*)d_in[2];
  const float* fk1c = (const float*)d_in[3];
  const float* fk1b = (const float*)d_in[4];
  const float* n2g = (const float*)d_in[5];
  const float* n2b = (const float*)d_in[6];
  const float* fk2c = (const float*)d_in[7];
  const float* fk2b = (const float*)d_in[8];
  const float* w1 = (const float*)d_in[9];
  const float* w2 = (const float*)d_in[10];
  const float* convw = (const float*)d_in[11];

  ushort_t* out2 = (ushort_t*)d_ws;        // 8,388,608 bf16 (16 MB)
  ushort_t* coefT = out2 + 8388608;        // 524,288 bf16 (1 MB)
  float* chanSum = (float*)(coefT + 524288);
  float* chanMax = chanSum + 2048;
  float* dout = (float*)d_out;

  prep_coef_k<<<256, 256, 0, stream>>>(fk1c, fk2c, coefT);
  fkan_main_k<<<1024, 256, 0, stream>>>(x, n1g, n1b, fk1b, n2g, n2b,
                                        fk2b, coefT, out2, chanSum, chanMax);
  tail_k<<<NB * 16, 128, 0, stream>>>(x, out2, chanSum, chanMax, w1, w2, convw, dout);
}

// Round 19
// 147.883 us; speedup vs baseline: 1.2969x; 1.2969x over previous
//
#include <hip/hip_runtime.h>
#include <math.h>

typedef unsigned short ushort_t;
typedef unsigned int uint_t;
typedef _Float16 half_t;

#define DIMC 128
#define NB 16
#define NL 4096

using f32x4 = __attribute__((ext_vector_type(4))) float;
using bf16x8 = __attribute__((ext_vector_type(8))) short;
using half4 = __attribute__((ext_vector_type(4))) half_t;

__device__ __forceinline__ ushort_t bf16rne(float f) {
  uint_t b = __float_as_uint(f);
  b += 0x7fffu + ((b >> 16) & 1u);
  return (ushort_t)(b >> 16);
}

__device__ __forceinline__ uint_t pkbf(float lo, float hi) {
  union { __bf16 h[2]; uint_t u; } u;
  u.h[0] = (__bf16)lo;   // fptrunc = RNE
  u.h[1] = (__bf16)hi;
  return u.u;
}

__device__ __forceinline__ float bf2f(ushort_t u) {
  return __uint_as_float(((uint_t)u) << 16);
}

// ---------------- kernel 0: coeffs -> B-fragment order, bf16 ----------------
// flat 16B-fragment id (per layer): G = ((ci*8 + n)*4 + s)*64 + l
// element j: col o = n*16 + (l&15); k = ci*128 + s*32 + (l>>4)*8 + j
// k -> trig=k&1, g=(k>>1)&7, i=k>>4 ; value = fk[trig][o][i][g]
__global__ __launch_bounds__(256) void prep_coef_k(const float* __restrict__ fk1,
                                                   const float* __restrict__ fk2,
                                                   ushort_t* __restrict__ coefT) {
  int idx = blockIdx.x * 256 + threadIdx.x;  // fragment id, 65536 total
  int layer = idx >> 15;
  int rem = idx & 32767;
  int ci = rem >> 11;
  int n = (rem >> 8) & 7;
  int s = (rem >> 6) & 3;
  int l = rem & 63;
  int o = n * 16 + (l & 15);
  int kbase = ci * 128 + s * 32 + (l >> 4) * 8;
  const float* src = layer ? fk2 : fk1;
  uint_t p[4];
#pragma unroll
  for (int jj = 0; jj < 4; ++jj) {
    int k0 = kbase + jj * 2;
    int t0 = k0 & 1, g0 = (k0 >> 1) & 7, i0 = k0 >> 4;
    int k1 = k0 + 1;
    int t1 = k1 & 1, g1 = (k1 >> 1) & 7, i1 = k1 >> 4;
    ushort_t a = bf16rne(src[((t0 * DIMC + o) * DIMC + i0) * 8 + g0]);
    ushort_t b = bf16rne(src[((t1 * DIMC + o) * DIMC + i1) * 8 + g1]);
    p[jj] = (uint_t)a | ((uint_t)b << 16);
  }
  uint4 w;
  w.x = p[0]; w.y = p[1]; w.z = p[2]; w.w = p[3];
  *(uint4*)&coefT[idx * 8] = w;
}

// ---------------- kernel 1: LN1 -> FKAN1(MFMA) -> ReLU -> LN2 -> FKAN2(MFMA) ----
// r17 spine (best measured, 107.5us): 512 blocks x 4 waves; wave owns 32
// tokens x 128 outputs end-to-end, zero barriers; wave-private LDS chain
// pipeline (1 chain/lane/step, zero featgen redundancy); HW trig + Chebyshev.
// NEW r19: A-fragments REGISTER-prefetched one step ahead -- af(j+1) ds_reads
// issue at the end of step j (after chain(j+1)'s ds_writes; same-wave DS is
// in-order), so their ~120cyc latency hides under step j+1's ldBs+chain and
// mfma16 starts from registers with no lgkm wait on the serial path.
constexpr int SXH = 132;  // xln row stride in halfwords (rows 8B-aligned)

__global__ __launch_bounds__(256, 2) void fkan_main_k(
    const float* __restrict__ x,
    const float* __restrict__ n1g, const float* __restrict__ n1b,
    const float* __restrict__ fk1b,
    const float* __restrict__ n2g, const float* __restrict__ n2b,
    const float* __restrict__ fk2b,
    const ushort_t* __restrict__ coefT,
    ushort_t* __restrict__ out2,
    float* __restrict__ chanSum, float* __restrict__ chanMax) {

  __shared__ half_t xln[128 * SXH];        // 33.8 KB, rows wave-private
  __shared__ uint4 feat[4][2][2][64];      // 16 KB: [wid][buf][mm][fraglane]

  const int tid = threadIdx.x;
  const int bid = blockIdx.x;                        // 512 blocks = 128 tokens each
  const int lane = tid & 63;
  const int wid = tid >> 6;
  const int rowBase = wid * 32;                      // wave's token rows in xln
  const size_t tileBase = (size_t)bid * 128 * DIMC;  // flat token = bid*128 + row

  {  // per-wave x-load: 32 rows x 128 f32, coalesced; store fp16 to LDS
    const float4* src = (const float4*)(x + tileBase + (size_t)rowBase * DIMC);
#pragma unroll
    for (int j = 0; j < 16; ++j) {
      int idx = j * 64 + lane;  // 0..1023
      float4 v = src[idx];
      half4 h;
      h.x = (half_t)v.x; h.y = (half_t)v.y; h.z = (half_t)v.z; h.w = (half_t)v.w;
      *(half4*)&xln[(rowBase + (idx >> 5)) * SXH + (idx & 31) * 4] = h;
    }
  }

  auto layernorm = [&](const float* gg, const float* bb) {
    float g0 = gg[lane], g1 = gg[lane + 64];
    float be0 = bb[lane], be1 = bb[lane + 64];
#pragma unroll
    for (int j = 0; j < 32; ++j) {
      int t = rowBase + j;
      float v0 = (float)xln[t * SXH + lane], v1 = (float)xln[t * SXH + 64 + lane];
      float s = v0 + v1, q = v0 * v0 + v1 * v1;
#pragma unroll
      for (int m = 1; m < 64; m <<= 1) {
        s += __shfl_xor(s, m, 64);
        q += __shfl_xor(q, m, 64);
      }
      float mean = s * (1.0f / DIMC);
      float var = q * (1.0f / DIMC) - mean * mean;
      float rr = rsqrtf(var + 1e-5f);
      xln[t * SXH + lane] = (half_t)((v0 - mean) * rr * g0 + be0);
      xln[t * SXH + 64 + lane] = (half_t)((v1 - mean) * rr * g1 + be1);
    }
  };

  layernorm(n1g, n1b);

  // chain layout constants (r13): lane handles token tl = lane&31, channel
  // offset chOff = lane>>5 of the step's channel pair; writes both fragment
  // halves as 16-lane-contiguous b128. Same-wave DS ordering: no barrier.
  const int tl = lane & 31;
  const int chOff = lane >> 5;
  const int mmw = tl >> 4;
  const int l0 = (tl & 15) + (chOff << 5);
  const half_t* xch = &xln[(rowBase + tl) * SXH + chOff];

  // angle fetch for a given flat step (chunk wraps harmlessly at 64+)
  auto angAt = [&](int step) -> float {
    int st = step & 63;
    return (float)xch[((st >> 2) & 15) * 8 + (st & 3) * 2];
  };

  // Chebyshev chain from preloaded angle: ck = 2c1*c(k-1) - c(k-2).
  // Native HW trig: v_sin/v_cos compute sin/cos(2*pi*x); reduce via fract.
  auto chain_cheb = [&](float a, int nbuf) {
    float r = a * 0.15915494309189535f;     // a / (2*pi)
    r = r - floorf(r);                      // fract -> [0,1)
    float s1 = __builtin_amdgcn_sinf(r);
    float c1 = __builtin_amdgcn_cosf(r);
    float tc = c1 + c1;
    float c2 = tc * c1 - 1.0f;
    float s2 = tc * s1;
    float c3 = tc * c2 - c1, s3 = tc * s2 - s1;
    float c4 = tc * c3 - c2, s4 = tc * s3 - s2;
    float c5 = tc * c4 - c3, s5 = tc * s4 - s3;
    float c6 = tc * c5 - c4, s6 = tc * s5 - s4;
    float c7 = tc * c6 - c5, s7 = tc * s6 - s5;
    float c8 = tc * c7 - c6, s8 = tc * s7 - s6;
    uint4 w0, w1;
    w0.x = pkbf(c1, s1); w0.y = pkbf(c2, s2);
    w0.z = pkbf(c3, s3); w0.w = pkbf(c4, s4);   // harmonics 1-4
    w1.x = pkbf(c5, s5); w1.y = pkbf(c6, s6);
    w1.z = pkbf(c7, s7); w1.w = pkbf(c8, s8);   // harmonics 5-8
    feat[wid][nbuf][mmw][l0] = w0;
    feat[wid][nbuf][mmw][l0 + 16] = w1;
  };

  f32x4 acc[8][2];

  auto ldBs = [&](const ushort_t* cbase, int step, bf16x8 (&bf)[8]) {
    int ci = (step >> 2) & 15, s = step & 3;
#pragma unroll
    for (int nn = 0; nn < 8; ++nn)
      bf[nn] = *(const bf16x8*)(cbase +
          (size_t)((((ci * 8 + nn) * 4 + s) << 6) + lane) * 8);
  };

  auto mfma16 = [&](bf16x8 a0, bf16x8 a1, bf16x8 (&bf)[8]) {
    __builtin_amdgcn_s_setprio(1);
#pragma unroll
    for (int nn = 0; nn < 8; ++nn) {
      acc[nn][0] = __builtin_amdgcn_mfma_f32_16x16x32_bf16(a0, bf[nn],
                                                           acc[nn][0], 0, 0, 0);
      acc[nn][1] = __builtin_amdgcn_mfma_f32_16x16x32_bf16(a1, bf[nn],
                                                           acc[nn][1], 0, 0, 0);
    }
    __builtin_amdgcn_s_setprio(0);
  };

  // barrier-free main loop (r17 spine + af register prefetch).
  // Per half-step j: ldBs(j); preload angle(j+3); chain(j+1) -> other buf;
  // mfma16 from REGISTERS (read at end of step j-1); then issue af(j+1)
  // ds_reads (after chain(j+1) wrote them; latency spans next ldBs+chain).
  auto run_layer = [&](const ushort_t* cbase) {
#pragma unroll
    for (int nn = 0; nn < 8; ++nn)
#pragma unroll
      for (int mm = 0; mm < 2; ++mm) acc[nn][mm] = (f32x4)(0.f);
    chain_cheb(angAt(0), 0);
    float aP1 = angAt(1);
    float aP2 = angAt(2);
    bf16x8 afA0 = *(const bf16x8*)&feat[wid][0][0][lane];  // step 0 frags
    bf16x8 afA1 = *(const bf16x8*)&feat[wid][0][1][lane];
    bf16x8 afB0, afB1;
#pragma unroll 1
    for (int it = 0; it < 32; ++it) {
      const int e = it * 2;
      {  // step e: consume afA (buf0), produce buf1, prefetch afB <- buf1
        bf16x8 bf[8];
        ldBs(cbase, e, bf);
        float aN = angAt(e + 3);
        chain_cheb(aP1, 1);
        mfma16(afA0, afA1, bf);
        afB0 = *(const bf16x8*)&feat[wid][1][0][lane];
        afB1 = *(const bf16x8*)&feat[wid][1][1][lane];
        aP1 = aP2; aP2 = aN;
      }
      {  // step e+1: consume afB (buf1), produce buf0, prefetch afA <- buf0
        bf16x8 bf[8];
        ldBs(cbase, e + 1, bf);
        float aN = angAt(e + 4);  // wraps at 64+: dead but safe
        chain_cheb(aP1, 0);
        mfma16(afB0, afB1, bf);
        afA0 = *(const bf16x8*)&feat[wid][0][0][lane];  // step 64 wrap: dead
        afA1 = *(const bf16x8*)&feat[wid][0][1][lane];
        aP1 = aP2; aP2 = aN;
      }
    }
  };

  run_layer(coefT);

  // FKAN1 epilogue: bias + ReLU -> xln (C/D: col=lane&15, row=(lane>>4)*4+r)
#pragma unroll
  for (int nn = 0; nn < 8; ++nn) {
    int o = nn * 16 + (lane & 15);
    float bia = fk1b[o];
#pragma unroll
    for (int mm = 0; mm < 2; ++mm) {
      int trow = rowBase + mm * 16 + (lane >> 4) * 4;
#pragma unroll
      for (int r = 0; r < 4; ++r)
        xln[(trow + r) * SXH + o] = (half_t)fmaxf(acc[nn][mm][r] + bia, 0.f);
    }
  }

  layernorm(n2g, n2b);

  run_layer(coefT + 262144);

  // FKAN2 epilogue: bias -> out2 (bf16) + this wave's channel-group stats
  float ls = 0.f, lm = -INFINITY;
#pragma unroll
  for (int nn = 0; nn < 8; ++nn) {
    int o = nn * 16 + (lane & 15);
    float bia = fk2b[o];
#pragma unroll
    for (int mm = 0; mm < 2; ++mm) {
      int trow = rowBase + mm * 16 + (lane >> 4) * 4;
#pragma unroll
      for (int r = 0; r < 4; ++r) {
        float v = acc[nn][mm][r] + bia;
        out2[tileBase + (size_t)(trow + r) * DIMC + o] = bf16rne(v);
        ls += v;
        lm = fmaxf(lm, v);
      }
    }
  }
#pragma unroll
  for (int m = 1; m < 64; m <<= 1) {
    ls += __shfl_xor(ls, m, 64);
    lm = fmaxf(lm, __shfl_xor(lm, m, 64));
  }
  if (lane == 0) {  // wave's 32 tokens = one LCBAM channel group
    chanSum[bid * 4 + wid] = ls;
    chanMax[bid * 4 + wid] = lm;
  }
}

// ---------------- kernel 2: fused tail (VECTORIZED: 2 channels/thread) ----
// Block covers one b and TWO t values; thread (tq = tid>>6, cp = tid&63)
// handles channels {2cp, 2cp+1} of t = t0+tq via ushort2/float2 accesses.
// Validated in r18 (passed, absmax 0.03125).
__global__ __launch_bounds__(128) void tail_k(
    const float* __restrict__ x, const ushort_t* __restrict__ out2,
    const float* __restrict__ chanSum, const float* __restrict__ chanMax,
    const float* __restrict__ w1, const float* __restrict__ w2,
    const float* __restrict__ convw, float* __restrict__ dout) {
  int b = blockIdx.x >> 4;
  int t0 = (blockIdx.x & 15) * 2;
  int tid = threadIdx.x;
  int c = tid;           // channel for the MLP phase
  int tq = tid >> 6;
  int cp = tid & 63;
  int t = t0 + tq;
  __shared__ float avs[DIMC], mxs[DIMC], hh[16], cas[DIMC];
  __shared__ float sM[2][134], sX[2][134];

  avs[c] = chanSum[b * DIMC + c] * (1.0f / NL);
  mxs[c] = chanMax[b * DIMC + c];
  __syncthreads();
  if (c < 16) {
    const float* v = (c < 8) ? avs : mxs;
    float a = 0.f;
    for (int i = 0; i < DIMC; ++i) a += v[i] * w1[(c & 7) * DIMC + i];
    hh[c] = fmaxf(a, 0.f);
  }
  __syncthreads();
  {
    float z = 0.f;
#pragma unroll
    for (int r = 0; r < 8; ++r) z += (hh[r] + hh[8 + r]) * w2[c * 8 + r];
    cas[c] = 1.0f / (1.0f + expf(-z));
  }
  __syncthreads();

  const ushort_t* o2b = out2 + (size_t)b * NL * DIMC;
  float s0 = 0.f, s1v = 0.f, m0 = -INFINITY, m1 = -INFINITY;
#pragma unroll 4
  for (int c4 = 0; c4 < 128; ++c4) {
    ushort2 u = *(const ushort2*)&o2b[(size_t)(c4 * 32 + t) * DIMC + 2 * cp];
    float ca = cas[c4];
    float v0 = bf2f(u.x) * ca, v1 = bf2f(u.y) * ca;
    s0 += v0; m0 = fmaxf(m0, v0);
    s1v += v1; m1 = fmaxf(m1, v1);
  }
  sM[tq][2 * cp + 3] = s0 * (1.0f / DIMC); sX[tq][2 * cp + 3] = m0;
  sM[tq][2 * cp + 4] = s1v * (1.0f / DIMC); sX[tq][2 * cp + 4] = m1;
  if (cp < 6) {  // halo positions for this t (zero-padded at sequence edges)
    bool left = cp < 3;
    int tp = left ? t - 1 : t + 1;
    int cc = left ? 125 + cp : cp - 3;
    int di = left ? cp : 131 + (cp - 3);
    float ss = 0.f, mm2 = -INFINITY;
    if (tp >= 0 && tp < 32) {
#pragma unroll 4
      for (int c4 = 0; c4 < 128; ++c4) {
        float v = bf2f(o2b[(size_t)(c4 * 32 + tp) * DIMC + cc]) * cas[c4];
        ss += v;
        mm2 = fmaxf(mm2, v);
      }
      sM[tq][di] = ss * (1.0f / DIMC);
      sX[tq][di] = mm2;
    } else {
      sM[tq][di] = 0.f;
      sX[tq][di] = 0.f;
    }
  }
  __syncthreads();

  float sa0 = 0.f, sa1 = 0.f;
#pragma unroll
  for (int d = 0; d < 7; ++d) {
    float wm = convw[21 + d], wx = convw[70 + d];
    sa0 += wm * sM[tq][2 * cp + d] + wx * sX[tq][2 * cp + d];
    sa1 += wm * sM[tq][2 * cp + 1 + d] + wx * sX[tq][2 * cp + 1 + d];
  }
  float sig0 = 1.0f / (1.0f + expf(-sa0));
  float sig1 = 1.0f / (1.0f + expf(-sa1));

  const float* xb = x + (size_t)b * NL * DIMC;
  float* db = dout + (size_t)b * NL * DIMC;
#pragma unroll 2
  for (int c4 = 0; c4 < 128; ++c4) {
    size_t idx = (size_t)(c4 * 32 + t) * DIMC + 2 * cp;
    float2 xv = *(const float2*)&xb[idx];
    ushort2 u = *(const ushort2*)&o2b[idx];
    float ca = cas[c4];
    float2 dv;
    dv.x = xv.x + bf2f(u.x) * ca * sig0;
    dv.y = xv.y + bf2f(u.y) * ca * sig1;
    *(float2*)&db[idx] = dv;
  }
}

// ---------------- launch ----------------
extern "C" void kernel_launch(void* const* d_in, const int* in_sizes, int n_in,
                              void* d_out, int out_size, void* d_ws, size_t ws_size,
                              hipStream_t stream) {
  const float* x = (const float*)d_in[0];
  const float* n1g = (const float*)d_in[1];
  const float* n1b = (const float*)d_in[2];
  const float* fk1c = (const float*)d_in[3];
  const float* fk1b = (const float*)d_in[4];
  const float* n2g = (const float*)d_in[5];
  const float* n2b = (const float*)d_in[6];
  const float* fk2c = (const float*)d_in[7];
  const float* fk2b = (const float*)d_in[8];
  const float* w1 = (const float*)d_in[9];
  const float* w2 = (const float*)d_in[10];
  const float* convw = (const float*)d_in[11];

  ushort_t* out2 = (ushort_t*)d_ws;        // 8,388,608 bf16 (16 MB)
  ushort_t* coefT = out2 + 8388608;        // 524,288 bf16 (1 MB)
  float* chanSum = (float*)(coefT + 524288);
  float* chanMax = chanSum + 2048;
  float* dout = (float*)d_out;

  prep_coef_k<<<256, 256, 0, stream>>>(fk1c, fk2c, coefT);
  fkan_main_k<<<512, 256, 0, stream>>>(x, n1g, n1b, fk1b, n2g, n2b,
                                       fk2b, coefT, out2, chanSum, chanMax);
  tail_k<<<NB * 16, 128, 0, stream>>>(x, out2, chanSum, chanMax, w1, w2, convw, dout);
}

// Round 20
// 130.268 us; speedup vs baseline: 1.4723x; 1.1352x over previous
//
#include <hip/hip_runtime.h>
#include <math.h>

typedef unsigned short ushort_t;
typedef unsigned int uint_t;
typedef _Float16 half_t;

#define DIMC 128
#define NB 16
#define NL 4096

using f32x4 = __attribute__((ext_vector_type(4))) float;
using bf16x8 = __attribute__((ext_vector_type(8))) short;
using half4 = __attribute__((ext_vector_type(4))) half_t;

__device__ __forceinline__ ushort_t bf16rne(float f) {
  uint_t b = __float_as_uint(f);
  b += 0x7fffu + ((b >> 16) & 1u);
  return (ushort_t)(b >> 16);
}

__device__ __forceinline__ uint_t pkbf(float lo, float hi) {
  union { __bf16 h[2]; uint_t u; } u;
  u.h[0] = (__bf16)lo;   // fptrunc = RNE
  u.h[1] = (__bf16)hi;
  return u.u;
}

__device__ __forceinline__ float bf2f(ushort_t u) {
  return __uint_as_float(((uint_t)u) << 16);
}

// ---------------- kernel 0: coeffs -> B-fragment order, bf16 ----------------
// flat 16B-fragment id (per layer): G = ((ci*8 + n)*4 + s)*64 + l
// element j: col o = n*16 + (l&15); k = ci*128 + s*32 + (l>>4)*8 + j
// k -> trig=k&1, g=(k>>1)&7, i=k>>4 ; value = fk[trig][o][i][g]
__global__ __launch_bounds__(256) void prep_coef_k(const float* __restrict__ fk1,
                                                   const float* __restrict__ fk2,
                                                   ushort_t* __restrict__ coefT) {
  int idx = blockIdx.x * 256 + threadIdx.x;  // fragment id, 65536 total
  int layer = idx >> 15;
  int rem = idx & 32767;
  int ci = rem >> 11;
  int n = (rem >> 8) & 7;
  int s = (rem >> 6) & 3;
  int l = rem & 63;
  int o = n * 16 + (l & 15);
  int kbase = ci * 128 + s * 32 + (l >> 4) * 8;
  const float* src = layer ? fk2 : fk1;
  uint_t p[4];
#pragma unroll
  for (int jj = 0; jj < 4; ++jj) {
    int k0 = kbase + jj * 2;
    int t0 = k0 & 1, g0 = (k0 >> 1) & 7, i0 = k0 >> 4;
    int k1 = k0 + 1;
    int t1 = k1 & 1, g1 = (k1 >> 1) & 7, i1 = k1 >> 4;
    ushort_t a = bf16rne(src[((t0 * DIMC + o) * DIMC + i0) * 8 + g0]);
    ushort_t b = bf16rne(src[((t1 * DIMC + o) * DIMC + i1) * 8 + g1]);
    p[jj] = (uint_t)a | ((uint_t)b << 16);
  }
  uint4 w;
  w.x = p[0]; w.y = p[1]; w.z = p[2]; w.w = p[3];
  *(uint4*)&coefT[idx * 8] = w;
}

// ---------------- kernel 1: LN1 -> FKAN1(MFMA) -> ReLU -> LN2 -> FKAN2(MFMA) ----
// r17/r19 spine (best measured, 107.5us, stable across 2 runs): 512 blocks x
// 4 waves; wave owns 32 tokens x 128 outputs end-to-end, zero barriers;
// wave-private LDS chain pipeline (1 chain/lane/step); HW trig + Chebyshev;
// angle preloaded 2 steps ahead; A-fragments register-prefetched one step.
constexpr int SXH = 132;  // xln row stride in halfwords (rows 8B-aligned)

__global__ __launch_bounds__(256, 2) void fkan_main_k(
    const float* __restrict__ x,
    const float* __restrict__ n1g, const float* __restrict__ n1b,
    const float* __restrict__ fk1b,
    const float* __restrict__ n2g, const float* __restrict__ n2b,
    const float* __restrict__ fk2b,
    const ushort_t* __restrict__ coefT,
    ushort_t* __restrict__ out2,
    float* __restrict__ chanSum, float* __restrict__ chanMax) {

  __shared__ half_t xln[128 * SXH];        // 33.8 KB, rows wave-private
  __shared__ uint4 feat[4][2][2][64];      // 16 KB: [wid][buf][mm][fraglane]

  const int tid = threadIdx.x;
  const int bid = blockIdx.x;                        // 512 blocks = 128 tokens each
  const int lane = tid & 63;
  const int wid = tid >> 6;
  const int rowBase = wid * 32;                      // wave's token rows in xln
  const size_t tileBase = (size_t)bid * 128 * DIMC;  // flat token = bid*128 + row

  {  // per-wave x-load: 32 rows x 128 f32, coalesced; store fp16 to LDS
    const float4* src = (const float4*)(x + tileBase + (size_t)rowBase * DIMC);
#pragma unroll
    for (int j = 0; j < 16; ++j) {
      int idx = j * 64 + lane;  // 0..1023
      float4 v = src[idx];
      half4 h;
      h.x = (half_t)v.x; h.y = (half_t)v.y; h.z = (half_t)v.z; h.w = (half_t)v.w;
      *(half4*)&xln[(rowBase + (idx >> 5)) * SXH + (idx & 31) * 4] = h;
    }
  }

  auto layernorm = [&](const float* gg, const float* bb) {
    float g0 = gg[lane], g1 = gg[lane + 64];
    float be0 = bb[lane], be1 = bb[lane + 64];
#pragma unroll
    for (int j = 0; j < 32; ++j) {
      int t = rowBase + j;
      float v0 = (float)xln[t * SXH + lane], v1 = (float)xln[t * SXH + 64 + lane];
      float s = v0 + v1, q = v0 * v0 + v1 * v1;
#pragma unroll
      for (int m = 1; m < 64; m <<= 1) {
        s += __shfl_xor(s, m, 64);
        q += __shfl_xor(q, m, 64);
      }
      float mean = s * (1.0f / DIMC);
      float var = q * (1.0f / DIMC) - mean * mean;
      float rr = rsqrtf(var + 1e-5f);
      xln[t * SXH + lane] = (half_t)((v0 - mean) * rr * g0 + be0);
      xln[t * SXH + 64 + lane] = (half_t)((v1 - mean) * rr * g1 + be1);
    }
  };

  layernorm(n1g, n1b);

  // chain layout constants (r13): lane handles token tl = lane&31, channel
  // offset chOff = lane>>5 of the step's channel pair; writes both fragment
  // halves as 16-lane-contiguous b128. Same-wave DS ordering: no barrier.
  const int tl = lane & 31;
  const int chOff = lane >> 5;
  const int mmw = tl >> 4;
  const int l0 = (tl & 15) + (chOff << 5);
  const half_t* xch = &xln[(rowBase + tl) * SXH + chOff];

  // angle fetch for a given flat step (chunk wraps harmlessly at 64+)
  auto angAt = [&](int step) -> float {
    int st = step & 63;
    return (float)xch[((st >> 2) & 15) * 8 + (st & 3) * 2];
  };

  // Chebyshev chain from preloaded angle: ck = 2c1*c(k-1) - c(k-2).
  // Native HW trig: v_sin/v_cos compute sin/cos(2*pi*x); reduce via fract.
  auto chain_cheb = [&](float a, int nbuf) {
    float r = a * 0.15915494309189535f;     // a / (2*pi)
    r = r - floorf(r);                      // fract -> [0,1)
    float s1 = __builtin_amdgcn_sinf(r);
    float c1 = __builtin_amdgcn_cosf(r);
    float tc = c1 + c1;
    float c2 = tc * c1 - 1.0f;
    float s2 = tc * s1;
    float c3 = tc * c2 - c1, s3 = tc * s2 - s1;
    float c4 = tc * c3 - c2, s4 = tc * s3 - s2;
    float c5 = tc * c4 - c3, s5 = tc * s4 - s3;
    float c6 = tc * c5 - c4, s6 = tc * s5 - s4;
    float c7 = tc * c6 - c5, s7 = tc * s6 - s5;
    float c8 = tc * c7 - c6, s8 = tc * s7 - s6;
    uint4 w0, w1;
    w0.x = pkbf(c1, s1); w0.y = pkbf(c2, s2);
    w0.z = pkbf(c3, s3); w0.w = pkbf(c4, s4);   // harmonics 1-4
    w1.x = pkbf(c5, s5); w1.y = pkbf(c6, s6);
    w1.z = pkbf(c7, s7); w1.w = pkbf(c8, s8);   // harmonics 5-8
    feat[wid][nbuf][mmw][l0] = w0;
    feat[wid][nbuf][mmw][l0 + 16] = w1;
  };

  f32x4 acc[8][2];

  auto ldBs = [&](const ushort_t* cbase, int step, bf16x8 (&bf)[8]) {
    int ci = (step >> 2) & 15, s = step & 3;
#pragma unroll
    for (int nn = 0; nn < 8; ++nn)
      bf[nn] = *(const bf16x8*)(cbase +
          (size_t)((((ci * 8 + nn) * 4 + s) << 6) + lane) * 8);
  };

  auto mfma16 = [&](bf16x8 a0, bf16x8 a1, bf16x8 (&bf)[8]) {
    __builtin_amdgcn_s_setprio(1);
#pragma unroll
    for (int nn = 0; nn < 8; ++nn) {
      acc[nn][0] = __builtin_amdgcn_mfma_f32_16x16x32_bf16(a0, bf[nn],
                                                           acc[nn][0], 0, 0, 0);
      acc[nn][1] = __builtin_amdgcn_mfma_f32_16x16x32_bf16(a1, bf[nn],
                                                           acc[nn][1], 0, 0, 0);
    }
    __builtin_amdgcn_s_setprio(0);
  };

  // barrier-free main loop (r17 spine + af register prefetch).
  auto run_layer = [&](const ushort_t* cbase) {
#pragma unroll
    for (int nn = 0; nn < 8; ++nn)
#pragma unroll
      for (int mm = 0; mm < 2; ++mm) acc[nn][mm] = (f32x4)(0.f);
    chain_cheb(angAt(0), 0);
    float aP1 = angAt(1);
    float aP2 = angAt(2);
    bf16x8 afA0 = *(const bf16x8*)&feat[wid][0][0][lane];  // step 0 frags
    bf16x8 afA1 = *(const bf16x8*)&feat[wid][0][1][lane];
    bf16x8 afB0, afB1;
#pragma unroll 1
    for (int it = 0; it < 32; ++it) {
      const int e = it * 2;
      {  // step e: consume afA (buf0), produce buf1, prefetch afB <- buf1
        bf16x8 bf[8];
        ldBs(cbase, e, bf);
        float aN = angAt(e + 3);
        chain_cheb(aP1, 1);
        mfma16(afA0, afA1, bf);
        afB0 = *(const bf16x8*)&feat[wid][1][0][lane];
        afB1 = *(const bf16x8*)&feat[wid][1][1][lane];
        aP1 = aP2; aP2 = aN;
      }
      {  // step e+1: consume afB (buf1), produce buf0, prefetch afA <- buf0
        bf16x8 bf[8];
        ldBs(cbase, e + 1, bf);
        float aN = angAt(e + 4);  // wraps at 64+: dead but safe
        chain_cheb(aP1, 0);
        mfma16(afB0, afB1, bf);
        afA0 = *(const bf16x8*)&feat[wid][0][0][lane];  // step 64 wrap: dead
        afA1 = *(const bf16x8*)&feat[wid][0][1][lane];
        aP1 = aP2; aP2 = aN;
      }
    }
  };

  run_layer(coefT);

  // FKAN1 epilogue: bias + ReLU -> xln (C/D: col=lane&15, row=(lane>>4)*4+r)
#pragma unroll
  for (int nn = 0; nn < 8; ++nn) {
    int o = nn * 16 + (lane & 15);
    float bia = fk1b[o];
#pragma unroll
    for (int mm = 0; mm < 2; ++mm) {
      int trow = rowBase + mm * 16 + (lane >> 4) * 4;
#pragma unroll
      for (int r = 0; r < 4; ++r)
        xln[(trow + r) * SXH + o] = (half_t)fmaxf(acc[nn][mm][r] + bia, 0.f);
    }
  }

  layernorm(n2g, n2b);

  run_layer(coefT + 262144);

  // FKAN2 epilogue: bias -> out2 (bf16) + this wave's channel-group stats
  float ls = 0.f, lm = -INFINITY;
#pragma unroll
  for (int nn = 0; nn < 8; ++nn) {
    int o = nn * 16 + (lane & 15);
    float bia = fk2b[o];
#pragma unroll
    for (int mm = 0; mm < 2; ++mm) {
      int trow = rowBase + mm * 16 + (lane >> 4) * 4;
#pragma unroll
      for (int r = 0; r < 4; ++r) {
        float v = acc[nn][mm][r] + bia;
        out2[tileBase + (size_t)(trow + r) * DIMC + o] = bf16rne(v);
        ls += v;
        lm = fmaxf(lm, v);
      }
    }
  }
#pragma unroll
  for (int m = 1; m < 64; m <<= 1) {
    ls += __shfl_xor(ls, m, 64);
    lm = fmaxf(lm, __shfl_xor(lm, m, 64));
  }
  if (lane == 0) {  // wave's 32 tokens = one LCBAM channel group
    chanSum[bid * 4 + wid] = ls;
    chanMax[bid * 4 + wid] = lm;
  }
}

// ---------------- kernel 2: fused tail, HIGH-OCCUPANCY ----
// One block per (b,t), 256 threads: c = tid&127, h = tid>>7; each h-half
// sweeps 64 of the 128 c4 channels (partials combined in LDS). 512 blocks x
// 4 waves = 8 waves/CU, unroll 8 -> enough outstanding loads to be BW-bound
// (r19's 128-thread tail was 1 wave/SIMD latency-bound at ~1.4 TB/s).
__global__ __launch_bounds__(256) void tail_k(
    const float* __restrict__ x, const ushort_t* __restrict__ out2,
    const float* __restrict__ chanSum, const float* __restrict__ chanMax,
    const float* __restrict__ w1, const float* __restrict__ w2,
    const float* __restrict__ convw, float* __restrict__ dout) {
  int b = blockIdx.x >> 5;
  int t = blockIdx.x & 31;
  int tid = threadIdx.x;
  int c = tid & 127;
  int h = tid >> 7;
  __shared__ float avs[DIMC], mxs[DIMC], hh[16], cas[DIMC];
  __shared__ float pS[2][DIMC], pM[2][DIMC];
  __shared__ float pHS[2][6], pHM[2][6];
  __shared__ float sM[134], sX[134], sig[DIMC];

  if (tid < DIMC) {
    avs[tid] = chanSum[b * DIMC + tid] * (1.0f / NL);
    mxs[tid] = chanMax[b * DIMC + tid];
  }
  __syncthreads();
  if (tid < 16) {
    const float* v = (tid < 8) ? avs : mxs;
    float a = 0.f;
    for (int i = 0; i < DIMC; ++i) a += v[i] * w1[(tid & 7) * DIMC + i];
    hh[tid] = fmaxf(a, 0.f);
  }
  __syncthreads();
  if (tid < DIMC) {
    float z = 0.f;
#pragma unroll
    for (int r = 0; r < 8; ++r) z += (hh[r] + hh[8 + r]) * w2[tid * 8 + r];
    cas[tid] = 1.0f / (1.0f + expf(-z));
  }
  __syncthreads();

  const ushort_t* o2b = out2 + (size_t)b * NL * DIMC;
  {  // main sweep: this half's 64 channels of position (t, c)
    float s = 0.f, m = -INFINITY;
#pragma unroll 8
    for (int q = 0; q < 64; ++q) {
      int c4 = h * 64 + q;
      float v = bf2f(o2b[(size_t)(c4 * 32 + t) * DIMC + c]) * cas[c4];
      s += v;
      m = fmaxf(m, v);
    }
    pS[h][c] = s;
    pM[h][c] = m;
  }
  if (c < 6) {  // halo positions (zero-padded at sequence edges)
    bool left = c < 3;
    int tp = left ? t - 1 : t + 1;
    int cc = left ? 125 + c : c - 3;
    float ss = 0.f, mm2 = -INFINITY;
    if (tp >= 0 && tp < 32) {
#pragma unroll 8
      for (int q = 0; q < 64; ++q) {
        int c4 = h * 64 + q;
        float v = bf2f(o2b[(size_t)(c4 * 32 + tp) * DIMC + cc]) * cas[c4];
        ss += v;
        mm2 = fmaxf(mm2, v);
      }
    }
    pHS[h][c] = ss;
    pHM[h][c] = mm2;
  }
  __syncthreads();
  if (tid < DIMC) {
    sM[tid + 3] = (pS[0][tid] + pS[1][tid]) * (1.0f / DIMC);
    sX[tid + 3] = fmaxf(pM[0][tid], pM[1][tid]);
  }
  if (tid >= DIMC && (tid - DIMC) < 6) {
    int j = tid - DIMC;
    bool left = j < 3;
    int tp = left ? t - 1 : t + 1;
    int di = left ? j : 131 + (j - 3);
    if (tp >= 0 && tp < 32) {
      sM[di] = (pHS[0][j] + pHS[1][j]) * (1.0f / DIMC);
      sX[di] = fmaxf(pHM[0][j], pHM[1][j]);
    } else {
      sM[di] = 0.f;
      sX[di] = 0.f;
    }
  }
  __syncthreads();
  if (tid < DIMC) {
    float sa = 0.f;
#pragma unroll
    for (int d = 0; d < 7; ++d)
      sa += convw[21 + d] * sM[tid + d] + convw[70 + d] * sX[tid + d];
    sig[tid] = 1.0f / (1.0f + expf(-sa));
  }
  __syncthreads();

  const float* xb = x + (size_t)b * NL * DIMC;
  float* db = dout + (size_t)b * NL * DIMC;
  float sg = sig[c];
#pragma unroll 8
  for (int q = 0; q < 64; ++q) {
    int c4 = h * 64 + q;
    size_t idx = (size_t)(c4 * 32 + t) * DIMC + c;
    db[idx] = xb[idx] + bf2f(o2b[idx]) * cas[c4] * sg;
  }
}

// ---------------- launch ----------------
extern "C" void kernel_launch(void* const* d_in, const int* in_sizes, int n_in,
                              void* d_out, int out_size, void* d_ws, size_t ws_size,
                              hipStream_t stream) {
  const float* x = (const float*)d_in[0];
  const float* n1g = (const float*)d_in[1];
  const float* n1b = (const float*)d_in[2];
  const float* fk1c = (const float*)d_in[3];
  const float* fk1b = (const float*)d_in[4];
  const float* n2g = (const float*)d_in[5];
  const float* n2b = (const float*)d_in[6];
  const float* fk2c = (const float*)d_in[7];
  const float* fk2b = (const float*)d_in[8];
  const float* w1 = (const float*)d_in[9];
  const float* w2 = (const float*)d_in[10];
  const float* convw = (const float*)d_in[11];

  ushort_t* out2 = (ushort_t*)d_ws;        // 8,388,608 bf16 (16 MB)
  ushort_t* coefT = out2 + 8388608;        // 524,288 bf16 (1 MB)
  float* chanSum = (float*)(coefT + 524288);
  float* chanMax = chanSum + 2048;
  float* dout = (float*)d_out;

  prep_coef_k<<<256, 256, 0, stream>>>(fk1c, fk2c, coefT);
  fkan_main_k<<<512, 256, 0, stream>>>(x, n1g, n1b, fk1b, n2g, n2b,
                                       fk2b, coefT, out2, chanSum, chanMax);
  tail_k<<<NB * 32, 256, 0, stream>>>(x, out2, chanSum, chanMax, w1, w2, convw, dout);
}